// Round 5
// baseline (211.189 us; speedup 1.0000x reference)
//
#include <hip/hip_runtime.h>
#include <hip/hip_bf16.h>

typedef __bf16 bf16;
typedef __bf16 bf16x8 __attribute__((ext_vector_type(8)));
typedef float f32x4 __attribute__((ext_vector_type(4)));
typedef float f32x2 __attribute__((ext_vector_type(2)));

#define BB 64
#define EMB 256
#define UNITS 512
#define POI 5000
#define KCAT 1280
#define SCLD 5024   // sc row stride (5000 padded to x32)
#define L2E 1.4426950408889634f

__device__ __forceinline__ float rcp_(float x){ return __builtin_amdgcn_rcpf(x); }
__device__ __forceinline__ float exp2_(float x){ return __builtin_amdgcn_exp2f(x); }

__device__ __forceinline__ bf16x8 cvt8(f32x4 a0, f32x4 a1){
  bf16x8 o;
#pragma unroll
  for(int j=0;j<4;j++){ o[j]=(bf16)a0[j]; o[4+j]=(bf16)a1[j]; }
  return o;
}

// ---- fp32-A x fp32-B(strided) MFMA tile: B cols consecutive across 16 lanes -> 64B lines.
__device__ __forceinline__ f32x4 mm16r(const float* __restrict__ ap, const float* __restrict__ B,
                                       int ldb, int K, int nc, int lane){
  int q = lane >> 4;
  f32x4 acc = {0.f,0.f,0.f,0.f};
  ap += q*8;
  const float* bp = B + (size_t)(q*8)*ldb + nc;
#pragma unroll 2
  for(int k0 = 0; k0 < K; k0 += 32){
    bf16x8 a = cvt8(*(const f32x4*)ap, *(const f32x4*)(ap+4));
    bf16x8 b;
#pragma unroll
    for(int j=0;j<8;j++) b[j] = (bf16)bp[(size_t)j*ldb];
    acc = __builtin_amdgcn_mfma_f32_16x16x32_bf16(a, b, acc, 0, 0, 0);
    ap += 32; bp += (size_t)32*ldb;
  }
  return acc;
}
__device__ __forceinline__ f32x4 mm16f(const float* __restrict__ A, const float* __restrict__ B,
                                       int lda, int ldb, int K, int mr, int nc, int lane){
  return mm16r(A + (size_t)mr*lda, B, ldb, K, nc, lane);
}

// ---- 64-row transpose tile (small matrices only): dstT[c][r] = src[r][c], bf16.
__device__ __forceinline__ void t64(const float* __restrict__ src, int srcLd, int nRv,
    int r0, int c0, int cW, bf16* __restrict__ dstT, int dstLd,
    int lane, int w){
  int r = r0 + lane;
  bool rv = r < nRv;
  int cw4 = cW >> 2;
  int cb = c0 + w*cw4;
  for(int c8=0;c8<cw4;c8+=8){
    int c = cb + c8;
    f32x4 v0={0.f,0.f,0.f,0.f}, v1={0.f,0.f,0.f,0.f};
    if(rv){ v0 = *(const f32x4*)(src + (size_t)r*srcLd + c);
            v1 = *(const f32x4*)(src + (size_t)r*srcLd + c + 4); }
#pragma unroll
    for(int j=0;j<4;j++){
      dstT[(size_t)(c+j)*dstLd + r]   = (bf16)v0[j];
      dstT[(size_t)(c+4+j)*dstLd + r] = (bf16)v1[j];
    }
  }
}

// ---- prep: embB pack, W1T/W2T (small), out=fc-bias, outc zero+catd, sumb+sc-pad. grid 177.
__global__ __launch_bounds__(256) void k_prep0(
    const float* __restrict__ emb, const float* __restrict__ W1, const float* __restrict__ W2,
    const float* __restrict__ fcb, const float* __restrict__ catd,
    float* __restrict__ out, float* __restrict__ outc,
    bf16* __restrict__ embB, bf16* __restrict__ W1Tb, bf16* __restrict__ W2Tb,
    float* __restrict__ sumb, float* __restrict__ sc){
  int bx = blockIdx.x, t = threadIdx.x, lane = t & 63, w = t >> 6;
  if(bx < 80){                       // embB: rows [bx*64,+64), coalesced fp32->bf16
    int r0 = bx*64;
    for(int ch = t; ch < 2048; ch += 256){
      int r = r0 + (ch >> 5), cc = (ch & 31)*8;
      if(r < POI){
        f32x4 v0 = *(const f32x4*)(emb + (size_t)r*EMB + cc);
        f32x4 v1 = *(const f32x4*)(emb + (size_t)r*EMB + cc + 4);
        *(bf16x8*)(embB + (size_t)r*EMB + cc) = cvt8(v0, v1);
      }
    }
  } else if(bx < 88){                // W1Tb [512][256]
    int i = bx - 80;
    t64(W1, UNITS, EMB, (i>>1)*64, (i&1)*256, 256, W1Tb, EMB, lane, w);
  } else if(bx < 104){               // W2Tb [512][512]
    int i = bx - 88;
    t64(W2, UNITS, UNITS, (i>>1)*64, (i&1)*256, 256, W2Tb, UNITS, lane, w);
  } else if(bx < 168){               // out row: init with fc bias (folds k_logits bias)
    int b = bx - 104;
    for(int n=t; n<POI; n+=256) out[(size_t)b*POI + n] = fcb[n];
  } else if(bx < 176){               // outc: zero ctx region + catd copy, 8 rows/block
    int base = (bx - 168)*8;
    for(int i=t; i<8*768; i+=256){
      int bb = base + i/768, c = i - (i/768)*768;
      if(c < 256) outc[(size_t)bb*KCAT + c] = 0.f;
      else        outc[(size_t)bb*KCAT + 512 + c] = catd[(size_t)bb*512 + (c-256)];
    }
  } else {                           // sumb init + sc k-pad zero
    if(t < BB) sumb[t] = 0.f;
    for(int i=t; i<BB*24; i+=256){
      int b = i/24, j = i - (i/24)*24;
      sc[(size_t)b*SCLD + POI + j] = 0.f;
    }
  }
}

// ---- merged GRU GEMMs, strided fp32 weights (64B-coalesced), x1 gather inlined.
// grid (96, 2, 2). y: 0 = x1@gruK (z=0: embB[x[b]], z=1: query), 1 = h0@gruR. z: k-half.
__global__ __launch_bounds__(256) void k_gru(const int* __restrict__ x, const float* __restrict__ query,
    const bf16* __restrict__ embB, const float* __restrict__ h0,
    const float* __restrict__ gruK, const float* __restrict__ gruR,
    float* __restrict__ xmP, float* __restrict__ hmP){
  int lane = threadIdx.x & 63, w = threadIdx.x >> 6;
  int col = blockIdx.x*16 + (lane & 15);
  int y = blockIdx.y, z = blockIdx.z;
  int mr = w*16 + (lane & 15);
  int q = lane >> 4;
  const float* bp = (y ? gruR : gruK) + (size_t)(z*256 + q*8)*1536 + col;
  float* C = (y ? hmP : xmP) + (size_t)z*BB*1536;
  f32x4 acc = {0.f,0.f,0.f,0.f};
  if(y == 0 && z == 0){
    const bf16* ap = embB + (size_t)x[mr]*EMB + q*8;
#pragma unroll 2
    for(int k0=0;k0<256;k0+=32){
      bf16x8 a = *(const bf16x8*)ap;
      bf16x8 b;
#pragma unroll
      for(int j=0;j<8;j++) b[j] = (bf16)bp[(size_t)j*1536];
      acc = __builtin_amdgcn_mfma_f32_16x16x32_bf16(a, b, acc, 0,0,0);
      ap += 32; bp += (size_t)32*1536;
    }
  } else {
    const float* apf = y ? (h0 + (size_t)mr*512 + z*256 + q*8)
                         : (query + (size_t)mr*256 + q*8);
#pragma unroll 2
    for(int k0=0;k0<256;k0+=32){
      bf16x8 a = cvt8(*(const f32x4*)apf, *(const f32x4*)(apf+4));
      bf16x8 b;
#pragma unroll
      for(int j=0;j<8;j++) b[j] = (bf16)bp[(size_t)j*1536];
      acc = __builtin_amdgcn_mfma_f32_16x16x32_bf16(a, b, acc, 0,0,0);
      apf += 32; bp += (size_t)32*1536;
    }
  }
  int rb = w*16 + (lane >> 4)*4;
#pragma unroll
  for(int r=0;r<4;r++) C[(size_t)(rb+r)*1536 + col] = acc[r];
}

// ---- GRU gates; grid (64,2) x 256 thr; sums the 2 k-split slabs
__global__ __launch_bounds__(256) void k_gates(const float* __restrict__ xmP, const float* __restrict__ hmP,
                        const float* __restrict__ bias, const float* __restrict__ h0,
                        float* __restrict__ hn, float* __restrict__ outc, float* __restrict__ dout){
  int b = blockIdx.x, u = blockIdx.y*256 + threadIdx.x;
  const float* x0 = xmP + b*1536; const float* x1s = xmP + (size_t)BB*1536 + b*1536;
  const float* h0s = hmP + b*1536; const float* h1s = hmP + (size_t)BB*1536 + b*1536;
  float xz = x0[u]      + x1s[u]      + bias[u];
  float xg = x0[512+u]  + x1s[512+u]  + bias[512+u];
  float xh = x0[1024+u] + x1s[1024+u] + bias[1024+u];
  float hz = h0s[u]      + h1s[u]      + bias[1536+u];
  float hg = h0s[512+u]  + h1s[512+u]  + bias[2048+u];
  float hh = h0s[1024+u] + h1s[1024+u] + bias[2560+u];
  float z = rcp_(1.f + exp2_(-L2E*(xz+hz)));
  float r = rcp_(1.f + exp2_(-L2E*(xg+hg)));
  float ca = xh + r*hh;
  ca = fminf(fmaxf(ca, -15.f), 15.f);
  float e = exp2_(2.f*L2E*ca);
  float hc = (e - 1.f)*rcp_(e + 1.f);
  float h = h0[(size_t)b*512+u];
  float v = z*h + (1.f - z)*hc;
  hn[(size_t)b*512+u] = v;
  outc[(size_t)b*KCAT + 256 + u] = v;
  dout[(size_t)POI*BB + (size_t)b*512 + u] = v;                       // state
  dout[(size_t)POI*BB + (size_t)BB*512 + (size_t)b*512 + u] = v;      // output_
}

// ---- Eq = exp2(clamp(2*log2e*(hn@W2 + b2))): grid 128 (4 r x 32 c), 4-way K-split, LDS reduce.
__global__ __launch_bounds__(256) void k_qproj(const float* __restrict__ hn, const bf16* __restrict__ W2Tb,
                        const float* __restrict__ W2b, float* __restrict__ Eq){
  __shared__ float accs[16][17];
  int t = threadIdx.x, lane = t & 63, w = t >> 6;
  int c16 = blockIdx.x & 31, r16 = blockIdx.x >> 5;
  for(int i=t;i<16*17;i+=256) ((float*)accs)[i] = 0.f;
  __syncthreads();
  int q = lane >> 4;
  int mr  = r16*16 + (lane & 15);
  int col = c16*16 + (lane & 15);
  const float* ap = hn + (size_t)mr*UNITS + w*128 + q*8;
  const bf16*  bp = W2Tb + (size_t)col*UNITS + w*128 + q*8;
  f32x4 acc = {0.f,0.f,0.f,0.f};
#pragma unroll
  for(int k0=0;k0<128;k0+=32){
    bf16x8 a = cvt8(*(const f32x4*)ap, *(const f32x4*)(ap+4));
    bf16x8 b = *(const bf16x8*)bp;
    acc = __builtin_amdgcn_mfma_f32_16x16x32_bf16(a,b,acc,0,0,0);
    ap += 32; bp += 32;
  }
#pragma unroll
  for(int r=0;r<4;r++) atomicAdd(&accs[q*4+r][lane & 15], acc[r]);
  __syncthreads();
  int r = t >> 4, c = t & 15;
  int colg = c16*16 + c;
  float v = (accs[r][c] + W2b[colg])*(2.f*L2E);
  Eq[(size_t)(r16*16+r)*UNITS + colg] = exp2_(fminf(fmaxf(v,-40.f),40.f));
}

// ---- fused vproj+score+exp+sum, grid 313 x 512 thr: 16 poi rows, FULL u=512 per block.
// stage 1: Ev[16p][512u] via MFMA (A-frags hoisted to regs) -> evsT[u][p] in LDS.
// stage 2: thread = (2p, b); score complete in-block -> exp2 in-register, store single
// sc slab, 8-lane shfl reduce -> one atomicAdd(sumb[b]) per (block,b). k_smax eliminated.
__global__ __launch_bounds__(512) void k_vscore(
    const bf16* __restrict__ embB, const bf16* __restrict__ W1Tb,
    const float* __restrict__ W1b, const float* __restrict__ Eq,
    const float* __restrict__ Vw, float* __restrict__ sc, float* __restrict__ sumb){
  __shared__ float evsT[512][20];      // [u][p(16)+pad]
  __shared__ float vws[512];
  int t = threadIdx.x, lane = t & 63, w = t >> 6;   // 8 waves
  int p0 = blockIdx.x*16;
  int q = lane >> 4;
  int mr = p0 + (lane & 15); if(mr > POI-1) mr = POI-1;   // clamp; masked in stage 2
  // hoist A fragments (one emb row per lane-column, K=256)
  bf16x8 afr[8];
  {
    const bf16* ap = embB + (size_t)mr*EMB + q*8;
#pragma unroll
    for(int k=0;k<8;k++){ afr[k] = *(const bf16x8*)ap; ap += 32; }
  }
#pragma unroll
  for(int i=0;i<4;i++){
    int colL = (w + 8*i)*16 + (lane & 15);          // u col 0..511
    const bf16* bp = W1Tb + (size_t)colL*EMB + q*8;
    f32x4 acc = {0.f,0.f,0.f,0.f};
#pragma unroll
    for(int k=0;k<8;k++){
      acc = __builtin_amdgcn_mfma_f32_16x16x32_bf16(afr[k], *(const bf16x8*)bp, acc, 0,0,0);
      bp += 32;
    }
    float bn = W1b[colL];
    f32x4 ev;
#pragma unroll
    for(int r=0;r<4;r++){
      float v = (acc[r] + bn)*(2.f*L2E);
      ev[r] = exp2_(fminf(fmaxf(v,-40.f),40.f));
    }
    *(f32x4*)&evsT[colL][q*4] = ev;                 // evsT[u][p]: p = q*4+r
  }
  vws[t] = Vw[t];
  __syncthreads();
  // stage 2: pg = p-pair 0..7, b = 0..63
  int pg = t & 7, b = t >> 3;
  const float* qrow = Eq + (size_t)b*UNITS;
  f32x2 s = {0.f, 0.f};
#pragma unroll 4
  for(int u4=0; u4<128; ++u4){
    f32x4 q4 = *(const f32x4*)&qrow[u4*4];
    f32x4 wv = *(const f32x4*)&vws[u4*4];
#pragma unroll
    for(int j=0;j<4;j++){
      f32x2 ev = *(const f32x2*)&evsT[u4*4+j][2*pg];
      s[0] += wv[j]*rcp_(ev[0]*q4[j] + 1.f);
      s[1] += wv[j]*rcp_(ev[1]*q4[j] + 1.f);
    }
  }
  // score = -2*s (softmax-invariant SW shift dropped); bounded |2s|<~60 -> exp2 safe in fp32
  int pA = p0 + 2*pg;
  float e0 = (pA   < POI) ? exp2_(-2.f*L2E*s[0]) : 0.f;
  float e1 = (pA+1 < POI) ? exp2_(-2.f*L2E*s[1]) : 0.f;
  float* srow = sc + (size_t)b*SCLD + pA;
  if(pA+1 < POI){ f32x2 e2 = {e0, e1}; *(f32x2*)srow = e2; }
  else if(pA < POI) srow[0] = e0;
  float ps = e0 + e1;
  ps += __shfl_xor(ps, 1);
  ps += __shfl_xor(ps, 2);
  ps += __shfl_xor(ps, 4);
  if(pg == 0) atomicAdd(&sumb[b], ps);
}

// ---- context = sc[64,5024] @ emb[5000,256] (strided fp32 B), split-K x79, scaled 1/sum
__global__ __launch_bounds__(256) void k_ctx(const float* __restrict__ wb, const float* __restrict__ emb,
                                             const float* __restrict__ sumb, float* __restrict__ outc){
  int lane = threadIdx.x & 63, w = threadIdx.x >> 6;
  int n = blockIdx.x*16 + (lane & 15);       // n < 256
  int ky = blockIdx.y;                        // 79 splits of 64 (last 32, rows clamped)
  int kbeg = ky*64;
  int mr = w*16 + (lane & 15);
  int q = lane >> 4;
  const float* ap = wb + (size_t)mr*SCLD + kbeg + q*8;
  f32x4 acc = {0.f,0.f,0.f,0.f};
  if(ky < 78){
    const float* bp = emb + (size_t)(kbeg + q*8)*EMB + n;
#pragma unroll 2
    for(int k0=0;k0<64;k0+=32){
      bf16x8 a = cvt8(*(const f32x4*)ap, *(const f32x4*)(ap+4));
      bf16x8 b;
#pragma unroll
      for(int j=0;j<8;j++) b[j] = (bf16)bp[(size_t)j*EMB];
      acc = __builtin_amdgcn_mfma_f32_16x16x32_bf16(a,b,acc,0,0,0);
      ap += 32; bp += (size_t)32*EMB;
    }
  } else {                                    // tail [4992,5024): wb pad=0, emb row clamped
    bf16x8 a = cvt8(*(const f32x4*)ap, *(const f32x4*)(ap+4));
    bf16x8 b;
#pragma unroll
    for(int j=0;j<8;j++){
      int k = kbeg + q*8 + j; int kc = k < POI ? k : POI-1;
      b[j] = (bf16)emb[(size_t)kc*EMB + n];
    }
    acc = __builtin_amdgcn_mfma_f32_16x16x32_bf16(a,b,acc,0,0,0);
  }
  int rb = w*16 + (lane >> 4)*4;
#pragma unroll
  for(int r=0;r<4;r++) atomicAdd(&outc[(size_t)(rb+r)*KCAT + n], acc[r]*rcp_(sumb[rb+r]));
}

// ---- logits: split-K x8, atomicAdd onto bias-preinitialized d_out. grid (313,8).
__global__ __launch_bounds__(256) void k_logits(const float* __restrict__ A, const float* __restrict__ Bw,
                        float* __restrict__ out){
  int lane = threadIdx.x & 63, w = threadIdx.x >> 6;
  int n = blockIdx.x*16 + (lane & 15);
  int nc = n < POI ? n : POI-1;
  int ky = blockIdx.y, kbeg = ky*160;         // 8 x 160 = 1280
  f32x4 acc = mm16f(A + kbeg, Bw + (size_t)kbeg*POI, KCAT, POI, 160,
                    w*16 + (lane & 15), nc, lane);
  int rb = w*16 + (lane >> 4)*4;
  if(n < POI){
#pragma unroll
    for(int r=0;r<4;r++) atomicAdd(&out[(size_t)(rb+r)*POI + n], acc[r]);
  }
}

extern "C" void kernel_launch(void* const* d_in, const int* in_sizes, int n_in,
                              void* d_out, int out_size, void* d_ws, size_t ws_size,
                              hipStream_t stream){
  const int*   x     = (const int*)d_in[0];
  const float* query = (const float*)d_in[1];
  const float* emb   = (const float*)d_in[2];
  // d_in[3] A_hat unused by reference
  const float* h0    = (const float*)d_in[4];
  const float* catd  = (const float*)d_in[5];
  const float* gruK  = (const float*)d_in[6];
  const float* gruR  = (const float*)d_in[7];
  const float* gruB  = (const float*)d_in[8];
  const float* W1    = (const float*)d_in[9];
  const float* W1b   = (const float*)d_in[10];
  const float* W2    = (const float*)d_in[11];
  const float* W2b   = (const float*)d_in[12];
  const float* Vw    = (const float*)d_in[13];
  // d_in[14] V_b: softmax-invariant, dropped
  const float* fcw   = (const float*)d_in[15];
  const float* fcb   = (const float*)d_in[16];
  float* out = (float*)d_out;

  char* ws = (char*)d_ws;
  size_t off = 0;
  auto alloc = [&](size_t bytes)->void*{ void* p = ws + off; off += (bytes + 255) & ~(size_t)255; return p; };
  float* outc   = (float*)alloc((size_t)BB*KCAT*4);
  float* xmP    = (float*)alloc((size_t)2*BB*1536*4);
  float* hmP    = (float*)alloc((size_t)2*BB*1536*4);
  float* hn     = (float*)alloc((size_t)BB*512*4);
  float* Eq     = (float*)alloc((size_t)BB*512*4);
  bf16*  embB   = (bf16*)alloc((size_t)POI*EMB*2);
  bf16*  W1Tb   = (bf16*)alloc((size_t)UNITS*EMB*2);
  bf16*  W2Tb   = (bf16*)alloc((size_t)UNITS*UNITS*2);
  float* sumb   = (float*)alloc((size_t)BB*4);
  float* sc     = (float*)alloc((size_t)BB*SCLD*4);   // single slab (NY=1)

  k_prep0  <<<177, 256, 0, stream>>>(emb, W1, W2, fcb, catd, out, outc,
                                     embB, W1Tb, W2Tb, sumb, sc);
  k_gru    <<<dim3(96,2,2), 256, 0, stream>>>(x, query, embB, h0, gruK, gruR, xmP, hmP);
  k_gates  <<<dim3(BB,2), 256, 0, stream>>>(xmP, hmP, gruB, h0, hn, outc, out);
  k_qproj  <<<128, 256, 0, stream>>>(hn, W2Tb, W2b, Eq);
  k_vscore <<<313, 512, 0, stream>>>(embB, W1Tb, W1b, Eq, Vw, sc, sumb);
  k_ctx    <<<dim3(16,79), 256, 0, stream>>>(sc, emb, sumb, outc);
  k_logits <<<dim3(313,8), 256, 0, stream>>>(outc, fcw, out);
}

// Round 6
// 190.832 us; speedup vs baseline: 1.1067x; 1.1067x over previous
//
#include <hip/hip_runtime.h>
#include <hip/hip_bf16.h>

typedef __bf16 bf16;
typedef __bf16 bf16x8 __attribute__((ext_vector_type(8)));
typedef float f32x4 __attribute__((ext_vector_type(4)));

#define BB 64
#define EMB 256
#define UNITS 512
#define POI 5000
#define KCAT 1280
#define SCLD 5024   // sc row stride (5000 padded to x32)
#define L2E 1.4426950408889634f

__device__ __forceinline__ float rcp_(float x){ return __builtin_amdgcn_rcpf(x); }
__device__ __forceinline__ float exp2_(float x){ return __builtin_amdgcn_exp2f(x); }

__device__ __forceinline__ bf16x8 cvt8(f32x4 a0, f32x4 a1){
  bf16x8 o;
#pragma unroll
  for(int j=0;j<4;j++){ o[j]=(bf16)a0[j]; o[4+j]=(bf16)a1[j]; }
  return o;
}

// ---- fp32-A x fp32-B(strided) MFMA tile: B cols consecutive across 16 lanes -> 64B lines.
__device__ __forceinline__ f32x4 mm16r(const float* __restrict__ ap, const float* __restrict__ B,
                                       int ldb, int K, int nc, int lane){
  int q = lane >> 4;
  f32x4 acc = {0.f,0.f,0.f,0.f};
  ap += q*8;
  const float* bp = B + (size_t)(q*8)*ldb + nc;
#pragma unroll 2
  for(int k0 = 0; k0 < K; k0 += 32){
    bf16x8 a = cvt8(*(const f32x4*)ap, *(const f32x4*)(ap+4));
    bf16x8 b;
#pragma unroll
    for(int j=0;j<8;j++) b[j] = (bf16)bp[(size_t)j*ldb];
    acc = __builtin_amdgcn_mfma_f32_16x16x32_bf16(a, b, acc, 0, 0, 0);
    ap += 32; bp += (size_t)32*ldb;
  }
  return acc;
}
__device__ __forceinline__ f32x4 mm16f(const float* __restrict__ A, const float* __restrict__ B,
                                       int lda, int ldb, int K, int mr, int nc, int lane){
  return mm16r(A + (size_t)mr*lda, B, ldb, K, nc, lane);
}

// ---- 64-row transpose tile (small matrices only): dstT[c][r] = src[r][c], bf16.
__device__ __forceinline__ void t64(const float* __restrict__ src, int srcLd, int nRv,
    int r0, int c0, int cW, bf16* __restrict__ dstT, int dstLd,
    int lane, int w){
  int r = r0 + lane;
  bool rv = r < nRv;
  int cw4 = cW >> 2;
  int cb = c0 + w*cw4;
  for(int c8=0;c8<cw4;c8+=8){
    int c = cb + c8;
    f32x4 v0={0.f,0.f,0.f,0.f}, v1={0.f,0.f,0.f,0.f};
    if(rv){ v0 = *(const f32x4*)(src + (size_t)r*srcLd + c);
            v1 = *(const f32x4*)(src + (size_t)r*srcLd + c + 4); }
#pragma unroll
    for(int j=0;j<4;j++){
      dstT[(size_t)(c+j)*dstLd + r]   = (bf16)v0[j];
      dstT[(size_t)(c+4+j)*dstLd + r] = (bf16)v1[j];
    }
  }
}

// ---- prep: embB pack, W1T/W2T (small), out=fc-bias, outc zero+catd, sumb+sc-pad. grid 177.
__global__ __launch_bounds__(256) void k_prep0(
    const float* __restrict__ emb, const float* __restrict__ W1, const float* __restrict__ W2,
    const float* __restrict__ fcb, const float* __restrict__ catd,
    float* __restrict__ out, float* __restrict__ outc,
    bf16* __restrict__ embB, bf16* __restrict__ W1Tb, bf16* __restrict__ W2Tb,
    float* __restrict__ sumb, float* __restrict__ sc){
  int bx = blockIdx.x, t = threadIdx.x, lane = t & 63, w = t >> 6;
  if(bx < 80){                       // embB: rows [bx*64,+64), coalesced fp32->bf16
    int r0 = bx*64;
    for(int ch = t; ch < 2048; ch += 256){
      int r = r0 + (ch >> 5), cc = (ch & 31)*8;
      if(r < POI){
        f32x4 v0 = *(const f32x4*)(emb + (size_t)r*EMB + cc);
        f32x4 v1 = *(const f32x4*)(emb + (size_t)r*EMB + cc + 4);
        *(bf16x8*)(embB + (size_t)r*EMB + cc) = cvt8(v0, v1);
      }
    }
  } else if(bx < 88){                // W1Tb [512][256]
    int i = bx - 80;
    t64(W1, UNITS, EMB, (i>>1)*64, (i&1)*256, 256, W1Tb, EMB, lane, w);
  } else if(bx < 104){               // W2Tb [512][512]
    int i = bx - 88;
    t64(W2, UNITS, UNITS, (i>>1)*64, (i&1)*256, 256, W2Tb, UNITS, lane, w);
  } else if(bx < 168){               // out row: init with fc bias (folds k_logits bias)
    int b = bx - 104;
    for(int n=t; n<POI; n+=256) out[(size_t)b*POI + n] = fcb[n];
  } else if(bx < 176){               // outc: zero ctx region + catd copy, 8 rows/block
    int base = (bx - 168)*8;
    for(int i=t; i<8*768; i+=256){
      int bb = base + i/768, c = i - (i/768)*768;
      if(c < 256) outc[(size_t)bb*KCAT + c] = 0.f;
      else        outc[(size_t)bb*KCAT + 512 + c] = catd[(size_t)bb*512 + (c-256)];
    }
  } else {                           // sumb init + sc slab0 k-pad zero
    if(t < BB) sumb[t] = 0.f;
    for(int i=t; i<BB*24; i+=256){
      int b = i/24, j = i - (i/24)*24;
      sc[(size_t)b*SCLD + POI + j] = 0.f;
    }
  }
}

// ---- merged GRU GEMMs, strided fp32 weights (64B-coalesced), x1 gather inlined.
// grid (96, 2, 2). y: 0 = x1@gruK (z=0: embB[x[b]], z=1: query), 1 = h0@gruR. z: k-half.
__global__ __launch_bounds__(256) void k_gru(const int* __restrict__ x, const float* __restrict__ query,
    const bf16* __restrict__ embB, const float* __restrict__ h0,
    const float* __restrict__ gruK, const float* __restrict__ gruR,
    float* __restrict__ xmP, float* __restrict__ hmP){
  int lane = threadIdx.x & 63, w = threadIdx.x >> 6;
  int col = blockIdx.x*16 + (lane & 15);
  int y = blockIdx.y, z = blockIdx.z;
  int mr = w*16 + (lane & 15);
  int q = lane >> 4;
  const float* bp = (y ? gruR : gruK) + (size_t)(z*256 + q*8)*1536 + col;
  float* C = (y ? hmP : xmP) + (size_t)z*BB*1536;
  f32x4 acc = {0.f,0.f,0.f,0.f};
  if(y == 0 && z == 0){
    const bf16* ap = embB + (size_t)x[mr]*EMB + q*8;
#pragma unroll 2
    for(int k0=0;k0<256;k0+=32){
      bf16x8 a = *(const bf16x8*)ap;
      bf16x8 b;
#pragma unroll
      for(int j=0;j<8;j++) b[j] = (bf16)bp[(size_t)j*1536];
      acc = __builtin_amdgcn_mfma_f32_16x16x32_bf16(a, b, acc, 0,0,0);
      ap += 32; bp += (size_t)32*1536;
    }
  } else {
    const float* apf = y ? (h0 + (size_t)mr*512 + z*256 + q*8)
                         : (query + (size_t)mr*256 + q*8);
#pragma unroll 2
    for(int k0=0;k0<256;k0+=32){
      bf16x8 a = cvt8(*(const f32x4*)apf, *(const f32x4*)(apf+4));
      bf16x8 b;
#pragma unroll
      for(int j=0;j<8;j++) b[j] = (bf16)bp[(size_t)j*1536];
      acc = __builtin_amdgcn_mfma_f32_16x16x32_bf16(a, b, acc, 0,0,0);
      apf += 32; bp += (size_t)32*1536;
    }
  }
  int rb = w*16 + (lane >> 4)*4;
#pragma unroll
  for(int r=0;r<4;r++) C[(size_t)(rb+r)*1536 + col] = acc[r];
}

// ---- GRU gates; grid (64,2) x 256 thr; sums the 2 k-split slabs
__global__ __launch_bounds__(256) void k_gates(const float* __restrict__ xmP, const float* __restrict__ hmP,
                        const float* __restrict__ bias, const float* __restrict__ h0,
                        float* __restrict__ hn, float* __restrict__ outc, float* __restrict__ dout){
  int b = blockIdx.x, u = blockIdx.y*256 + threadIdx.x;
  const float* x0 = xmP + b*1536; const float* x1s = xmP + (size_t)BB*1536 + b*1536;
  const float* h0s = hmP + b*1536; const float* h1s = hmP + (size_t)BB*1536 + b*1536;
  float xz = x0[u]      + x1s[u]      + bias[u];
  float xg = x0[512+u]  + x1s[512+u]  + bias[512+u];
  float xh = x0[1024+u] + x1s[1024+u] + bias[1024+u];
  float hz = h0s[u]      + h1s[u]      + bias[1536+u];
  float hg = h0s[512+u]  + h1s[512+u]  + bias[2048+u];
  float hh = h0s[1024+u] + h1s[1024+u] + bias[2560+u];
  float z = rcp_(1.f + exp2_(-L2E*(xz+hz)));
  float r = rcp_(1.f + exp2_(-L2E*(xg+hg)));
  float ca = xh + r*hh;
  ca = fminf(fmaxf(ca, -15.f), 15.f);
  float e = exp2_(2.f*L2E*ca);
  float hc = (e - 1.f)*rcp_(e + 1.f);
  float h = h0[(size_t)b*512+u];
  float v = z*h + (1.f - z)*hc;
  hn[(size_t)b*512+u] = v;
  outc[(size_t)b*KCAT + 256 + u] = v;
  dout[(size_t)POI*BB + (size_t)b*512 + u] = v;                       // state
  dout[(size_t)POI*BB + (size_t)BB*512 + (size_t)b*512 + u] = v;      // output_
}

// ---- Eq = exp2(clamp(2*log2e*(hn@W2 + b2))): grid 128 (4 r x 32 c), 4-way K-split, LDS reduce.
__global__ __launch_bounds__(256) void k_qproj(const float* __restrict__ hn, const bf16* __restrict__ W2Tb,
                        const float* __restrict__ W2b, float* __restrict__ Eq){
  __shared__ float accs[16][17];
  int t = threadIdx.x, lane = t & 63, w = t >> 6;
  int c16 = blockIdx.x & 31, r16 = blockIdx.x >> 5;
  for(int i=t;i<16*17;i+=256) ((float*)accs)[i] = 0.f;
  __syncthreads();
  int q = lane >> 4;
  int mr  = r16*16 + (lane & 15);
  int col = c16*16 + (lane & 15);
  const float* ap = hn + (size_t)mr*UNITS + w*128 + q*8;
  const bf16*  bp = W2Tb + (size_t)col*UNITS + w*128 + q*8;
  f32x4 acc = {0.f,0.f,0.f,0.f};
#pragma unroll
  for(int k0=0;k0<128;k0+=32){
    bf16x8 a = cvt8(*(const f32x4*)ap, *(const f32x4*)(ap+4));
    bf16x8 b = *(const bf16x8*)bp;
    acc = __builtin_amdgcn_mfma_f32_16x16x32_bf16(a,b,acc,0,0,0);
    ap += 32; bp += 32;
  }
#pragma unroll
  for(int r=0;r<4;r++) atomicAdd(&accs[q*4+r][lane & 15], acc[r]);
  __syncthreads();
  int r = t >> 4, c = t & 15;
  int colg = c16*16 + c;
  float v = (accs[r][c] + W2b[colg])*(2.f*L2E);
  Eq[(size_t)(r16*16+r)*UNITS + colg] = exp2_(fminf(fmaxf(v,-40.f),40.f));
}

// ---- fused vproj+score, grid (313, 8): 16 poi rows x 64-u slice per block (R3 best form).
// stage 1: bf16 MFMA (embB x W1Tb, contiguous 16B loads) -> evsT[u][p] in LDS.
// stage 2: thread = (p-quad, b): 1 global Eq f32x4 per 48 VALU, ev via 4-way LDS broadcast.
__global__ __launch_bounds__(256, 8) void k_vscore(
    const bf16* __restrict__ embB, const bf16* __restrict__ W1Tb,
    const float* __restrict__ W1b, const float* __restrict__ Eq,
    const float* __restrict__ Vw, float* __restrict__ scS){
  __shared__ float evsT[64][20];      // [u_local][p_local(16) + pad]
  __shared__ float vws[64];
  int t = threadIdx.x, lane = t & 63, w = t >> 6;
  int p0 = blockIdx.x*16, uh = blockIdx.y*64;
  int q = lane >> 4;
  int mr = p0 + (lane & 15); if(mr > POI-1) mr = POI-1;
  {
    int colL = w*16 + (lane & 15);
    const bf16* ap = embB + (size_t)mr*EMB + q*8;
    const bf16* bp = W1Tb + (size_t)(uh+colL)*EMB + q*8;
    f32x4 acc = {0.f,0.f,0.f,0.f};
#pragma unroll
    for(int k0=0;k0<EMB;k0+=32){
      bf16x8 a = *(const bf16x8*)ap, b = *(const bf16x8*)bp;
      acc = __builtin_amdgcn_mfma_f32_16x16x32_bf16(a,b,acc,0,0,0);
      ap += 32; bp += 32;
    }
    float bn = W1b[uh+colL];
    f32x4 ev;
#pragma unroll
    for(int r=0;r<4;r++){
      float v = (acc[r] + bn)*(2.f*L2E);
      ev[r] = exp2_(fminf(fmaxf(v,-40.f),40.f));
    }
    *(f32x4*)&evsT[colL][q*4] = ev;    // transposed: 4 consecutive p
  }
  if(t < 64) vws[t] = Vw[uh + t];
  __syncthreads();
  int pg = t & 3, b = t >> 2;
  const float* qrow = Eq + (size_t)b*UNITS + uh;
  f32x4 s = {0.f,0.f,0.f,0.f};
#pragma unroll 4
  for(int u4=0; u4<16; ++u4){
    f32x4 q4 = *(const f32x4*)&qrow[u4*4];
    f32x4 wv = *(const f32x4*)&vws[u4*4];
#pragma unroll
    for(int j=0;j<4;j++){
      f32x4 ev = *(const f32x4*)&evsT[u4*4+j][4*pg];
#pragma unroll
      for(int e=0;e<4;e++)
        s[e] += wv[j]*rcp_(ev[e]*q4[j] + 1.f);
    }
  }
  int pA = p0 + 4*pg;
  float* srow = scS + (size_t)blockIdx.y*BB*SCLD + (size_t)b*SCLD + pA;
  if(pA + 3 < POI) *(f32x4*)srow = s;
  else {
#pragma unroll
    for(int e=0;e<4;e++) if(pA+e < POI) srow[e] = s[e];
  }
}

// ---- single-pass softmax numerator: e = exp(-2*sum_y sc_y) (bounded; SW shift cancels);
//      atomicAdd per-b sum into sumb. grid (64,8).
__global__ __launch_bounds__(256) void k_smax(float* __restrict__ sc, float* __restrict__ sumb){
  __shared__ float red[256];
  int b = blockIdx.x, y = blockIdx.y, t = threadIdx.x;
  float* sA = sc + (size_t)b*SCLD;
  int pend = (y+1)*640; if(pend > POI) pend = POI;
  float sm = 0.f;
  for(int p = y*640 + t; p < pend; p += 256){
    float acc = sA[p];
#pragma unroll
    for(int s2=1;s2<8;s2++) acc += sA[(size_t)s2*BB*SCLD + p];
    float e = exp2_(-2.f*L2E*acc);
    sA[p] = e;                         // unnormalized; k_ctx applies 1/sum
    sm += e;
  }
  red[t] = sm; __syncthreads();
  for(int o=128;o>0;o>>=1){ if(t<o) red[t]+=red[t+o]; __syncthreads(); }
  if(t==0) atomicAdd(sumb + b, red[0]);
}

// ---- context = sc[64,5024] @ emb[5000,256] (strided fp32 B), split-K x79, scaled 1/sum
__global__ __launch_bounds__(256) void k_ctx(const float* __restrict__ wb, const float* __restrict__ emb,
                                             const float* __restrict__ sumb, float* __restrict__ outc){
  int lane = threadIdx.x & 63, w = threadIdx.x >> 6;
  int n = blockIdx.x*16 + (lane & 15);       // n < 256
  int ky = blockIdx.y;                        // 79 splits of 64 (last 32, rows clamped)
  int kbeg = ky*64;
  int mr = w*16 + (lane & 15);
  int q = lane >> 4;
  const float* ap = wb + (size_t)mr*SCLD + kbeg + q*8;
  f32x4 acc = {0.f,0.f,0.f,0.f};
  if(ky < 78){
    const float* bp = emb + (size_t)(kbeg + q*8)*EMB + n;
#pragma unroll 2
    for(int k0=0;k0<64;k0+=32){
      bf16x8 a = cvt8(*(const f32x4*)ap, *(const f32x4*)(ap+4));
      bf16x8 b;
#pragma unroll
      for(int j=0;j<8;j++) b[j] = (bf16)bp[(size_t)j*EMB];
      acc = __builtin_amdgcn_mfma_f32_16x16x32_bf16(a,b,acc,0,0,0);
      ap += 32; bp += (size_t)32*EMB;
    }
  } else {                                    // tail [4992,5024): wb pad=0, emb row clamped
    bf16x8 a = cvt8(*(const f32x4*)ap, *(const f32x4*)(ap+4));
    bf16x8 b;
#pragma unroll
    for(int j=0;j<8;j++){
      int k = kbeg + q*8 + j; int kc = k < POI ? k : POI-1;
      b[j] = (bf16)emb[(size_t)kc*EMB + n];
    }
    acc = __builtin_amdgcn_mfma_f32_16x16x32_bf16(a,b,acc,0,0,0);
  }
  int rb = w*16 + (lane >> 4)*4;
#pragma unroll
  for(int r=0;r<4;r++) atomicAdd(&outc[(size_t)(rb+r)*KCAT + n], acc[r]*rcp_(sumb[rb+r]));
}

// ---- logits: split-K x4 (fewer atomics), atomicAdd onto bias-preinit d_out. grid (313,4).
__global__ __launch_bounds__(256) void k_logits(const float* __restrict__ A, const float* __restrict__ Bw,
                        float* __restrict__ out){
  int lane = threadIdx.x & 63, w = threadIdx.x >> 6;
  int n = blockIdx.x*16 + (lane & 15);
  int nc = n < POI ? n : POI-1;
  int ky = blockIdx.y, kbeg = ky*320;         // 4 x 320 = 1280
  f32x4 acc = mm16f(A + kbeg, Bw + (size_t)kbeg*POI, KCAT, POI, 320,
                    w*16 + (lane & 15), nc, lane);
  int rb = w*16 + (lane >> 4)*4;
  if(n < POI){
#pragma unroll
    for(int r=0;r<4;r++) atomicAdd(&out[(size_t)(rb+r)*POI + n], acc[r]);
  }
}

extern "C" void kernel_launch(void* const* d_in, const int* in_sizes, int n_in,
                              void* d_out, int out_size, void* d_ws, size_t ws_size,
                              hipStream_t stream){
  const int*   x     = (const int*)d_in[0];
  const float* query = (const float*)d_in[1];
  const float* emb   = (const float*)d_in[2];
  // d_in[3] A_hat unused by reference
  const float* h0    = (const float*)d_in[4];
  const float* catd  = (const float*)d_in[5];
  const float* gruK  = (const float*)d_in[6];
  const float* gruR  = (const float*)d_in[7];
  const float* gruB  = (const float*)d_in[8];
  const float* W1    = (const float*)d_in[9];
  const float* W1b   = (const float*)d_in[10];
  const float* W2    = (const float*)d_in[11];
  const float* W2b   = (const float*)d_in[12];
  const float* Vw    = (const float*)d_in[13];
  // d_in[14] V_b: softmax-invariant, dropped
  const float* fcw   = (const float*)d_in[15];
  const float* fcb   = (const float*)d_in[16];
  float* out = (float*)d_out;

  char* ws = (char*)d_ws;
  size_t off = 0;
  auto alloc = [&](size_t bytes)->void*{ void* p = ws + off; off += (bytes + 255) & ~(size_t)255; return p; };
  float* outc   = (float*)alloc((size_t)BB*KCAT*4);
  float* xmP    = (float*)alloc((size_t)2*BB*1536*4);
  float* hmP    = (float*)alloc((size_t)2*BB*1536*4);
  float* hn     = (float*)alloc((size_t)BB*512*4);
  float* Eq     = (float*)alloc((size_t)BB*512*4);
  bf16*  embB   = (bf16*)alloc((size_t)POI*EMB*2);
  bf16*  W1Tb   = (bf16*)alloc((size_t)UNITS*EMB*2);
  bf16*  W2Tb   = (bf16*)alloc((size_t)UNITS*UNITS*2);
  float* sumb   = (float*)alloc((size_t)BB*4);
  float* sc     = (float*)alloc((size_t)8*BB*SCLD*4);   // 8 u-slice slabs

  k_prep0  <<<177, 256, 0, stream>>>(emb, W1, W2, fcb, catd, out, outc,
                                     embB, W1Tb, W2Tb, sumb, sc);
  k_gru    <<<dim3(96,2,2), 256, 0, stream>>>(x, query, embB, h0, gruK, gruR, xmP, hmP);
  k_gates  <<<dim3(BB,2), 256, 0, stream>>>(xmP, hmP, gruB, h0, hn, outc, out);
  k_qproj  <<<128, 256, 0, stream>>>(hn, W2Tb, W2b, Eq);
  k_vscore <<<dim3(313,8), 256, 0, stream>>>(embB, W1Tb, W1b, Eq, Vw, sc);
  k_smax   <<<dim3(BB,8), 256, 0, stream>>>(sc, sumb);
  k_ctx    <<<dim3(16,79), 256, 0, stream>>>(sc, emb, sumb, outc);
  k_logits <<<dim3(313,4), 256, 0, stream>>>(outc, fcw, out);
}